// Round 4
// baseline (318.909 us; speedup 1.0000x reference)
//
#include <hip/hip_runtime.h>

// SparseLinearAttention: B=1, L=4096, H=16, D=64, BLKQ=BLKK=64, M=N=64, T=8.
// fp32 I/O; sparse-attn, kvsum, linear-out use bf16 MFMA 16x16x32, fp32 accum.

#define NH   16
#define DH   64
#define NBLK 64
#define TSEL 8

typedef unsigned short u16;
typedef unsigned int   u32;
typedef __attribute__((ext_vector_type(8))) short short8;  // 8 bf16
typedef __attribute__((ext_vector_type(4))) float f4;

#define MFMA_BF16(a, b, c) __builtin_amdgcn_mfma_f32_16x16x32_bf16(a, b, c, 0, 0, 0)

__device__ __forceinline__ u16 f2bf_rne(float f) {
  u32 u = __float_as_uint(f);
  u += 0x7fffu + ((u >> 16) & 1u);
  return (u16)(u >> 16);
}
__device__ __forceinline__ u32 pk2(float a, float b) {
  return (u32)f2bf_rne(a) | ((u32)f2bf_rne(b) << 16);
}
__device__ __forceinline__ float bf2f(u16 u) { return __uint_as_float(((u32)u) << 16); }

// Read an 8-bf16 MFMA fragment from a swizzled row-major bf16 tile
// (128 B rows; logical 16B-block j stored at j^(row&7)).
__device__ __forceinline__ short8 frag_row(const u16* lds, int row, int jblk) {
  int bp = jblk ^ (row & 7);
  return *(const short8*)((const char*)lds + row * 128 + bp * 16);
}

// ---------------- K1: block-mean partials (row-split by 16) -----------------
// grid (64 m, 4 rs, 2 src), 256 thr. Each iteration reads one full 4KB row
// (all 16 heads) fully coalesced. Unnormalized sums (scale is monotone).
__global__ __launch_bounds__(256) void means_kernel(const float* __restrict__ q,
                                                    const float* __restrict__ k,
                                                    float* __restrict__ qkp) {
  int m = blockIdx.x, rs = blockIdx.y, z = blockIdx.z;
  const float* src = z ? k : q;
  int tid = threadIdx.x;
  const float* base = src + ((size_t)(m * 64 + rs * 16)) * 1024 + tid * 4;
  float4 acc = {0.f, 0.f, 0.f, 0.f};
#pragma unroll
  for (int i = 0; i < 16; i++) {
    float4 a = *(const float4*)(base + (size_t)i * 1024);
    acc.x += a.x; acc.y += a.y; acc.z += a.z; acc.w += a.w;
  }
  *(float4*)(qkp + ((size_t)((z * 4 + rs) * 64 + m)) * 1024 + tid * 4) = acc;
}

// ---------------- K2: block scores + top-8 per (h,m) -> lut -----------------
__global__ __launch_bounds__(64) void topk_kernel(const float* __restrict__ qkp,
                                                  int* __restrict__ lut) {
  __shared__ __align__(16) float qr_s[64];
  int m = blockIdx.x, h = blockIdx.y, n = threadIdx.x;
  float qsum = 0.f;
#pragma unroll
  for (int rs = 0; rs < 4; rs++)
    qsum += qkp[((size_t)(rs * 64 + m)) * 1024 + h * 64 + n];
  qr_s[n] = qsum;
  __syncthreads();
  float s = 0.f;
#pragma unroll
  for (int rs = 0; rs < 4; rs++) {
    const float* kr = qkp + ((size_t)((4 + rs) * 64 + n)) * 1024 + h * 64;
#pragma unroll
    for (int d = 0; d < 64; d += 4) {
      float4 a = *(const float4*)(kr + d);
      float4 b = *(const float4*)(&qr_s[d]);
      s += a.x * b.x + a.y * b.y + a.z * b.z + a.w * b.w;
    }
  }
  float my = s;
  for (int t = 0; t < TSEL; t++) {
    float v = my; int idx = n;
#pragma unroll
    for (int off = 1; off < 64; off <<= 1) {
      float ov = __shfl_xor(v, off);
      int oi = __shfl_xor(idx, off);
      if (ov > v || (ov == v && oi < idx)) { v = ov; idx = oi; }
    }
    if (n == 0) lut[(h * NBLK + m) * TSEL + t] = idx;
    if (n == idx) my = -INFINITY;
  }
}

// ---------------- K3: block-sparse attention, 4-wave split-T, pipelined -----
// grid (16 h, 64 m), 256 thr = 4 waves; wave owns 2 of the 8 key blocks.
// K prefetched to regs (next-block prefetch during PV); V loads issued before
// S so they fly during S+softmax. 4-way flash merge via LDS atomics.
__global__ __launch_bounds__(256, 2) void sparse_attn_kernel(const float* __restrict__ q,
                                                             const float* __restrict__ k,
                                                             const float* __restrict__ v,
                                                             const int* __restrict__ lut,
                                                             float* __restrict__ out) {
  __shared__ __align__(16) char smem[73728];
  int h = blockIdx.x, m = blockIdx.y;
  int tid = threadIdx.x;
  int w = tid >> 6, lane = tid & 63;
  int lq = lane & 15, quad = lane >> 4;
  u16* q_l = (u16*)smem;
  char* kp_b = smem + 8192 + w * 16384;   // K tile, then P tile (wave-private)
  char* vt_b = kp_b + 8192;               // V^T tile (wave-private)

  { // stage Q (256 thr x 2 chunks), bf16 swizzled
#pragma unroll
    for (int c = 0; c < 2; c++) {
      int lo = c * 4096 + tid * 16;
      int r = lo >> 7;
      int j = ((lo >> 4) & 7) ^ (r & 7);
      const float* gp = q + ((size_t)(m * 64 + r)) * 1024 + h * 64 + j * 8;
      float4 a = *(const float4*)gp;
      float4 b = *(const float4*)(gp + 4);
      *(uint4*)(smem + lo) = make_uint4(pk2(a.x, a.y), pk2(a.z, a.w),
                                        pk2(b.x, b.y), pk2(b.z, b.w));
    }
  }
  __syncthreads();

  const int lb = (h * NBLK + m) * TSEL;
  int blks[2] = {lut[lb + w * 2], lut[lb + w * 2 + 1]};

  float4 ka[8], kb[8];   // K prefetch regs
  {
    const float* kbase = k + ((size_t)blks[0] * 64) * 1024 + h * 64;
#pragma unroll
    for (int c = 0; c < 8; c++) {
      int lo = c * 1024 + lane * 16;
      int r = lo >> 7;
      int j = ((lo >> 4) & 7) ^ (r & 7);
      const float* gp = kbase + (size_t)r * 1024 + j * 8;
      ka[c] = *(const float4*)gp;
      kb[c] = *(const float4*)(gp + 4);
    }
  }

  f4 o[4][4];  // O^T frags: e = et*16+quad*4+r, q = qt*16+lq
  f4 zz = {0.f, 0.f, 0.f, 0.f};
#pragma unroll
  for (int et = 0; et < 4; et++)
#pragma unroll
    for (int qt = 0; qt < 4; qt++) o[et][qt] = zz;
  float mrun[4], lrun[4];
#pragma unroll
  for (int i = 0; i < 4; i++) { mrun[i] = -INFINITY; lrun[i] = 0.f; }

  for (int it = 0; it < 2; it++) {
    // store prefetched K -> LDS (bf16 swizzled)
#pragma unroll
    for (int c = 0; c < 8; c++) {
      int lo = c * 1024 + lane * 16;
      *(uint4*)(kp_b + lo) = make_uint4(pk2(ka[c].x, ka[c].y), pk2(ka[c].z, ka[c].w),
                                        pk2(kb[c].x, kb[c].y), pk2(kb[c].z, kb[c].w));
    }
    // issue V loads now; consumed after softmax
    float4 va[16];
    const float* vbase = v + ((size_t)blks[it] * 64 + lane) * 1024 + h * 64;
#pragma unroll
    for (int c = 0; c < 16; c++) va[c] = *(const float4*)(vbase + c * 4);

    // S^T = K·Q^T
    f4 s[4][4];
#pragma unroll
    for (int kt = 0; kt < 4; kt++)
#pragma unroll
      for (int qt = 0; qt < 4; qt++) s[kt][qt] = zz;
#pragma unroll
    for (int ks = 0; ks < 2; ks++) {
      short8 afr[4], bfr[4];
#pragma unroll
      for (int kt = 0; kt < 4; kt++) afr[kt] = frag_row((u16*)kp_b, kt * 16 + lq, 4 * ks + quad);
#pragma unroll
      for (int qt = 0; qt < 4; qt++) bfr[qt] = frag_row(q_l, qt * 16 + lq, 4 * ks + quad);
#pragma unroll
      for (int kt = 0; kt < 4; kt++)
#pragma unroll
        for (int qt = 0; qt < 4; qt++)
          s[kt][qt] = MFMA_BF16(afr[kt], bfr[qt], s[kt][qt]);
    }

    // online softmax; P[q][key] written as packed b64 into kp_b
#pragma unroll
    for (int qt = 0; qt < 4; qt++) {
      float mp = -INFINITY;
#pragma unroll
      for (int kt = 0; kt < 4; kt++)
#pragma unroll
        for (int r = 0; r < 4; r++) mp = fmaxf(mp, s[kt][qt][r]);
      mp = fmaxf(mp, __shfl_xor(mp, 16));
      mp = fmaxf(mp, __shfl_xor(mp, 32));
      mp *= 0.125f;
      float mn = fmaxf(mrun[qt], mp);
      float al = __expf(mrun[qt] - mn);
      mrun[qt] = mn;
      int qrow = qt * 16 + lq;
      float rs_ = 0.f;
#pragma unroll
      for (int kt = 0; kt < 4; kt++) {
        float p0 = __expf(fmaf(s[kt][qt][0], 0.125f, -mn));
        float p1 = __expf(fmaf(s[kt][qt][1], 0.125f, -mn));
        float p2 = __expf(fmaf(s[kt][qt][2], 0.125f, -mn));
        float p3 = __expf(fmaf(s[kt][qt][3], 0.125f, -mn));
        rs_ += p0 + p1 + p2 + p3;
        u32 lo32 = (__float_as_uint(p0) >> 16) | (__float_as_uint(p1) & 0xffff0000u);
        u32 hi32 = (__float_as_uint(p2) >> 16) | (__float_as_uint(p3) & 0xffff0000u);
        int addr = qrow * 128 + ((kt * 2 + (quad >> 1)) ^ (qrow & 7)) * 16 + (quad & 1) * 8;
        *(uint2*)(kp_b + addr) = make_uint2(lo32, hi32);
      }
      rs_ += __shfl_xor(rs_, 16);
      rs_ += __shfl_xor(rs_, 32);
      lrun[qt] = lrun[qt] * al + rs_;
#pragma unroll
      for (int et = 0; et < 4; et++)
#pragma unroll
        for (int r = 0; r < 4; r++) o[et][qt][r] *= al;
    }

    // store V^T (scalar transpose scatter, swizzled)
    {
      int kbi = lane >> 3, klo = lane & 7;
#pragma unroll
      for (int c4 = 0; c4 < 16; c4++) {
        float vv[4] = {va[c4].x, va[c4].y, va[c4].z, va[c4].w};
#pragma unroll
        for (int jj = 0; jj < 4; jj++) {
          int e = c4 * 4 + jj;
          int bp = kbi ^ (e & 7);
          *(u16*)(vt_b + e * 128 + bp * 16 + klo * 2) = f2bf_rne(vv[jj]);
        }
      }
    }

    // prefetch next K during PV
    if (it == 0) {
      const float* kbase = k + ((size_t)blks[1] * 64) * 1024 + h * 64;
#pragma unroll
      for (int c = 0; c < 8; c++) {
        int lo = c * 1024 + lane * 16;
        int r = lo >> 7;
        int j = ((lo >> 4) & 7) ^ (r & 7);
        const float* gp = kbase + (size_t)r * 1024 + j * 8;
        ka[c] = *(const float4*)gp;
        kb[c] = *(const float4*)(gp + 4);
      }
    }

    // O^T += Vt·P^T
#pragma unroll
    for (int ks = 0; ks < 2; ks++) {
      short8 av[4], bp_[4];
#pragma unroll
      for (int et = 0; et < 4; et++) av[et] = frag_row((u16*)vt_b, et * 16 + lq, 4 * ks + quad);
#pragma unroll
      for (int qt = 0; qt < 4; qt++) bp_[qt] = frag_row((u16*)kp_b, qt * 16 + lq, 4 * ks + quad);
#pragma unroll
      for (int et = 0; et < 4; et++)
#pragma unroll
        for (int qt = 0; qt < 4; qt++)
          o[et][qt] = MFMA_BF16(av[et], bp_[qt], o[et][qt]);
    }
  }

  // ---- 4-way flash merge ----
  __syncthreads();   // all waves done with their slabs
  float* o_acc = (float*)smem;              // 64 x 65 fp32
  float* m_l  = (float*)(smem + 16640);     // [4][64]
  float* l2_l = (float*)(smem + 17664);     // [4][64]
  for (int i = tid; i < 4160; i += 256) o_acc[i] = 0.f;
  if (quad == 0) {
#pragma unroll
    for (int qt = 0; qt < 4; qt++) m_l[w * 64 + qt * 16 + lq] = mrun[qt];
  }
  __syncthreads();
#pragma unroll
  for (int qt = 0; qt < 4; qt++) {
    int qrow = qt * 16 + lq;
    float gm = fmaxf(fmaxf(m_l[qrow], m_l[64 + qrow]),
                     fmaxf(m_l[128 + qrow], m_l[192 + qrow]));
    float fac = __expf(mrun[qt] - gm);
    if (quad == 0) l2_l[w * 64 + qrow] = lrun[qt] * fac;
#pragma unroll
    for (int et = 0; et < 4; et++)
#pragma unroll
      for (int r = 0; r < 4; r++)
        atomicAdd(&o_acc[qrow * 65 + et * 16 + quad * 4 + r], o[et][qt][r] * fac);
  }
  __syncthreads();
  {
    int row = tid >> 2, cs = (tid & 3) * 16;
    float lt_ = l2_l[row] + l2_l[64 + row] + l2_l[128 + row] + l2_l[192 + row];
    float inv = 1.0f / lt_;
    float* gp = out + ((size_t)(m * 64 + row)) * 1024 + h * 64 + cs;
#pragma unroll
    for (int jj = 0; jj < 4; jj++) {
      float4 ov;
      ov.x = o_acc[row * 65 + cs + jj * 4 + 0] * inv;
      ov.y = o_acc[row * 65 + cs + jj * 4 + 1] * inv;
      ov.z = o_acc[row * 65 + cs + jj * 4 + 2] * inv;
      ov.w = o_acc[row * 65 + cs + jj * 4 + 3] * inv;
      *(float4*)(gp + jj * 4) = ov;
    }
  }
}

// ---------------- K4: kvsum partial slabs via MFMA --------------------------
// grid (16, 16 h), 256 thr = 4 waves; wave owns one 64-row chunk. LDS-combine
// 4 waves -> one fp32 slab per block (deterministic).
__global__ __launch_bounds__(256) void kvsum_kernel(const float* __restrict__ k,
                                                    const float* __restrict__ v,
                                                    float* __restrict__ kvp,
                                                    float* __restrict__ ksp) {
  __shared__ __align__(16) char slabs[65536];   // per wave: V^T 8KB + kfmT 8KB
  __shared__ float ks_red[256];
  int bx = blockIdx.x, h = blockIdx.y;
  int tid = threadIdx.x, w = tid >> 6, lane = tid & 63;
  int lq = lane & 15, quad = lane >> 4;
  char* vt_b = slabs + w * 16384;
  char* kf_b = vt_b + 8192;
  int n = bx * 4 + w;
  const float* kb_ = k + ((size_t)n * 64) * 1024 + h * 64;
  const float* vb_ = v + ((size_t)n * 64) * 1024 + h * 64;

  { // stage V^T
    const float* gp = vb_ + (size_t)lane * 1024;
    int kbi = lane >> 3, klo = lane & 7;
#pragma unroll
    for (int c4 = 0; c4 < 16; c4++) {
      float4 a = *(const float4*)(gp + c4 * 4);
      float vv[4] = {a.x, a.y, a.z, a.w};
#pragma unroll
      for (int jj = 0; jj < 4; jj++) {
        int e = c4 * 4 + jj;
        int bp = kbi ^ (e & 7);
        *(u16*)(vt_b + e * 128 + bp * 16 + klo * 2) = f2bf_rne(vv[jj]);
      }
    }
  }
  { // row softmax of K (lane = row), transposed store -> kfmT
    const float* kr = kb_ + (size_t)lane * 1024;
    float kv[64];
#pragma unroll
    for (int c4 = 0; c4 < 16; c4++) {
      float4 a = *(const float4*)(kr + c4 * 4);
      kv[c4 * 4] = a.x; kv[c4 * 4 + 1] = a.y; kv[c4 * 4 + 2] = a.z; kv[c4 * 4 + 3] = a.w;
    }
    float mx = -INFINITY;
#pragma unroll
    for (int d = 0; d < 64; d++) mx = fmaxf(mx, kv[d]);
    float sum = 0.f;
#pragma unroll
    for (int d = 0; d < 64; d++) { kv[d] = __expf(kv[d] - mx); sum += kv[d]; }
    float inv = 1.0f / sum;
    int rb = lane >> 3, rlo = lane & 7;
#pragma unroll
    for (int d = 0; d < 64; d++) {
      int bp = rb ^ (d & 7);
      *(u16*)(kf_b + d * 128 + bp * 16 + rlo * 2) = f2bf_rne(kv[d] * inv);
    }
  }
  // ksum partial (lane = d)
  float ksacc = 0.f;
#pragma unroll
  for (int jb = 0; jb < 8; jb++) {
    short8 x = frag_row((u16*)kf_b, lane, jb);
#pragma unroll
    for (int e = 0; e < 8; e++) ksacc += bf2f((u16)x[e]);
  }
  // MFMA: kvchunk = kfm^T @ v
  f4 acc[4][4];
  f4 zz = {0.f, 0.f, 0.f, 0.f};
#pragma unroll
  for (int dt = 0; dt < 4; dt++)
#pragma unroll
    for (int et = 0; et < 4; et++) acc[dt][et] = zz;
#pragma unroll
  for (int ks2 = 0; ks2 < 2; ks2++) {
    short8 a_[4], b_[4];
#pragma unroll
    for (int dt = 0; dt < 4; dt++) a_[dt] = frag_row((u16*)kf_b, dt * 16 + lq, 4 * ks2 + quad);
#pragma unroll
    for (int et = 0; et < 4; et++) b_[et] = frag_row((u16*)vt_b, et * 16 + lq, 4 * ks2 + quad);
#pragma unroll
    for (int dt = 0; dt < 4; dt++)
#pragma unroll
      for (int et = 0; et < 4; et++)
        acc[dt][et] = MFMA_BF16(a_[dt], b_[et], acc[dt][et]);
  }
  // combine 4 waves (reuse slabs as fp32 scratch), wave 0 writes slab
  float* red = (float*)(slabs + w * 16384);
  if (w > 0) {
#pragma unroll
    for (int dt = 0; dt < 4; dt++)
#pragma unroll
      for (int et = 0; et < 4; et++)
#pragma unroll
        for (int r = 0; r < 4; r++)
          red[(dt * 16 + quad * 4 + r) * 64 + et * 16 + lq] = acc[dt][et][r];
  }
  ks_red[w * 64 + lane] = ksacc;
  __syncthreads();
  if (w == 0) {
    float* r1 = (float*)(slabs + 16384);
    float* r2 = (float*)(slabs + 32768);
    float* r3 = (float*)(slabs + 49152);
    float* kvb = kvp + ((size_t)(bx * 16 + h)) * 4096;
#pragma unroll
    for (int dt = 0; dt < 4; dt++)
#pragma unroll
      for (int et = 0; et < 4; et++)
#pragma unroll
        for (int r = 0; r < 4; r++) {
          int idx = (dt * 16 + quad * 4 + r) * 64 + et * 16 + lq;
          kvb[idx] = acc[dt][et][r] + r1[idx] + r2[idx] + r3[idx];
        }
    ksp[(bx * 16 + h) * 64 + lane] = ks_red[lane] + ks_red[64 + lane] +
                                     ks_red[128 + lane] + ks_red[192 + lane];
  }
}

// ---------------- K5: reduce 16 slabs -> kvr, ksum --------------------------
__global__ __launch_bounds__(256) void reduce_kernel(const float* __restrict__ kvp,
                                                     const float* __restrict__ ksp,
                                                     float* __restrict__ kvr,
                                                     float* __restrict__ ksum) {
  int b = blockIdx.x;
  int h = b >> 4, seg = b & 15;
  int tid = threadIdx.x;
  int idx = seg * 256 + tid;
  float s = 0.f;
#pragma unroll
  for (int t = 0; t < 16; t++) s += kvp[((size_t)(t * 16 + h)) * 4096 + idx];
  kvr[h * 4096 + idx] = s;
  if (seg == 0 && tid < 64) {
    float ss = 0.f;
#pragma unroll
    for (int t = 0; t < 16; t++) ss += ksp[(t * 16 + h) * 64 + tid];
    ksum[h * 64 + tid] = ss;
  }
}

// ---------------- K6: M2^T = (kvsum @ W^T)^T as swizzled bf16 ---------------
__global__ __launch_bounds__(256) void m2_kernel(const float* __restrict__ kvr,
                                                 const float* __restrict__ wgt,
                                                 u16* __restrict__ m2t) {
  __shared__ float kv_s[64 * 65];
  __shared__ float w_s[64 * 65];
  int h = blockIdx.x, tid = threadIdx.x;
#pragma unroll
  for (int jj = 0; jj < 16; jj++) {
    int idx = tid * 16 + jj;
    kv_s[(idx >> 6) * 65 + (idx & 63)] = kvr[h * 4096 + idx];
    w_s[(idx >> 6) * 65 + (idx & 63)] = wgt[idx];
  }
  __syncthreads();
  int d = tid >> 2, e0 = (tid & 3) * 16;
  float acc[16];
#pragma unroll
  for (int e = 0; e < 16; e++) acc[e] = 0.f;
  for (int j = 0; j < 64; j++) {
    float kvj = kv_s[d * 65 + j];
#pragma unroll
    for (int e = 0; e < 16; e++)
      acc[e] = fmaf(kvj, w_s[(e0 + e) * 65 + j], acc[e]);
  }
  char* base = (char*)m2t + (size_t)h * 8192;
#pragma unroll
  for (int e = 0; e < 16; e++) {
    int ee = e0 + e;
    int bp = (d >> 3) ^ (ee & 7);
    *(u16*)(base + ee * 128 + bp * 16 + (d & 7) * 2) = f2bf_rne(acc[e]);
  }
}

// ---------------- K7: linear attention output via MFMA, out += o_l ----------
// grid (16 lg, 16 h), 256 thr = 4 waves; wave owns 64 sequence rows.
__global__ __launch_bounds__(256) void linear_out_kernel(const float* __restrict__ q,
                                                         const u16* __restrict__ m2t,
                                                         const float* __restrict__ ksum,
                                                         const float* __restrict__ bproj,
                                                         float* __restrict__ out) {
  __shared__ __align__(16) char lsm[42496];
  // [0,8192) m2t | [8192+w*8192, +8192) E/oL slab | 40960 ks | 41216 bias | 41472 sc[4][64]
  u16* m2_l = (u16*)lsm;
  int lg = blockIdx.x, h = blockIdx.y;
  int tid = threadIdx.x, w = tid >> 6, lane = tid & 63;
  int lq = lane & 15, quad = lane >> 4;
  char* e_b = lsm + 8192 + w * 8192;
  float* ks_s = (float*)(lsm + 40960);
  float* b_s  = (float*)(lsm + 41216);
  float* sc_s = (float*)(lsm + 41472);

  {
    const uint4* src = (const uint4*)((const char*)m2t + (size_t)h * 8192);
    ((uint4*)lsm)[tid] = src[tid];
    ((uint4*)lsm)[256 + tid] = src[256 + tid];
  }
  if (tid < 64) { ks_s[tid] = ksum[h * 64 + tid]; b_s[tid] = bproj[tid]; }
  __syncthreads();

  int l = (lg * 4 + w) * 64 + lane;
  const float* qp = q + (size_t)l * 1024 + h * 64;
  float qv[64];
#pragma unroll
  for (int c4 = 0; c4 < 16; c4++) {
    float4 a = *(const float4*)(qp + c4 * 4);
    qv[c4 * 4] = a.x; qv[c4 * 4 + 1] = a.y; qv[c4 * 4 + 2] = a.z; qv[c4 * 4 + 3] = a.w;
  }
  float mx = -INFINITY;
#pragma unroll
  for (int d = 0; d < 64; d++) mx = fmaxf(mx, qv[d]);
  float sum = 0.f, eks = 0.f;
#pragma unroll
  for (int d = 0; d < 64; d++) {
    float e = __expf(qv[d] - mx);
    qv[d] = e;
    sum += e;
    eks += e * ks_s[d];
  }
  float inv = 1.0f / sum;
  float den = fmaf(eks, inv, 1e-6f);
  sc_s[w * 64 + lane] = inv / den;

  { // write E row (bf16, swizzled)
    int rowm = lane & 7;
#pragma unroll
    for (int jb = 0; jb < 8; jb++) {
      int d0 = jb * 8;
      uint4 pv = make_uint4(pk2(qv[d0], qv[d0 + 1]), pk2(qv[d0 + 2], qv[d0 + 3]),
                            pk2(qv[d0 + 4], qv[d0 + 5]), pk2(qv[d0 + 6], qv[d0 + 7]));
      *(uint4*)(e_b + lane * 128 + ((jb ^ rowm) * 16)) = pv;
    }
  }

  // O_l^T frags: a = m2t rows (e), b = E rows (l): C[e][l]
  f4 oc[4][4];
  f4 zz = {0.f, 0.f, 0.f, 0.f};
#pragma unroll
  for (int et = 0; et < 4; et++)
#pragma unroll
    for (int lt = 0; lt < 4; lt++) oc[et][lt] = zz;
#pragma unroll
  for (int ks2 = 0; ks2 < 2; ks2++) {
    short8 a_[4], b_[4];
#pragma unroll
    for (int et = 0; et < 4; et++) a_[et] = frag_row(m2_l, et * 16 + lq, 4 * ks2 + quad);
#pragma unroll
    for (int lt = 0; lt < 4; lt++) b_[lt] = frag_row((u16*)e_b, lt * 16 + lq, 4 * ks2 + quad);
#pragma unroll
    for (int et = 0; et < 4; et++)
#pragma unroll
      for (int lt = 0; lt < 4; lt++)
        oc[et][lt] = MFMA_BF16(a_[et], b_[lt], oc[et][lt]);
  }

  // scaled+biased o_l -> bf16 slab (b64 packs), then coalesced RMW to out
#pragma unroll
  for (int lt = 0; lt < 4; lt++) {
    int lrow = lt * 16 + lq;
    float sc2 = sc_s[w * 64 + lrow];
#pragma unroll
    for (int et = 0; et < 4; et++) {
      int e0 = et * 16 + quad * 4;
      float p0 = oc[et][lt][0] * sc2 + b_s[e0 + 0];
      float p1 = oc[et][lt][1] * sc2 + b_s[e0 + 1];
      float p2 = oc[et][lt][2] * sc2 + b_s[e0 + 2];
      float p3 = oc[et][lt][3] * sc2 + b_s[e0 + 3];
      int addr = lrow * 128 + ((et * 2 + (quad >> 1)) ^ (lrow & 7)) * 16 + (quad & 1) * 8;
      *(uint2*)(e_b + addr) = make_uint2(pk2(p0, p1), pk2(p2, p3));
    }
  }
  {
    float* gp = out + (size_t)l * 1024 + h * 64;
    int rowm = lane & 7;
#pragma unroll
    for (int jb = 0; jb < 8; jb++) {
      uint4 x = *(const uint4*)(e_b + lane * 128 + ((jb ^ rowm) * 16));
      float4 o1 = *(const float4*)(gp + jb * 8);
      float4 o2 = *(const float4*)(gp + jb * 8 + 4);
      o1.x += __uint_as_float(x.x << 16);
      o1.y += __uint_as_float(x.x & 0xffff0000u);
      o1.z += __uint_as_float(x.y << 16);
      o1.w += __uint_as_float(x.y & 0xffff0000u);
      o2.x += __uint_as_float(x.z << 16);
      o2.y += __uint_as_float(x.z & 0xffff0000u);
      o2.z += __uint_as_float(x.w << 16);
      o2.w += __uint_as_float(x.w & 0xffff0000u);
      *(float4*)(gp + jb * 8) = o1;
      *(float4*)(gp + jb * 8 + 4) = o2;
    }
  }
}

extern "C" void kernel_launch(void* const* d_in, const int* in_sizes, int n_in,
                              void* d_out, int out_size, void* d_ws, size_t ws_size,
                              hipStream_t stream) {
  const float* q = (const float*)d_in[0];
  const float* k = (const float*)d_in[1];
  const float* v = (const float*)d_in[2];
  const float* w = (const float*)d_in[3];
  const float* b = (const float*)d_in[4];
  float* out = (float*)d_out;

  // ws (fp32 words unless noted): qkp 512K | lut 8K int | kvp 1M | ksp 16K |
  //                               kvr 64K | ksum 1K | m2t 64K u16
  float* qkp = (float*)d_ws;
  int* lut = (int*)(qkp + 524288);
  float* kvp = (float*)(lut + 8192);
  float* ksp = kvp + 1048576;
  float* kvr = ksp + 16384;
  float* ksum = kvr + 65536;
  u16* m2t = (u16*)(ksum + 1024);

  means_kernel<<<dim3(64, 4, 2), 256, 0, stream>>>(q, k, qkp);
  topk_kernel<<<dim3(64, 16), 64, 0, stream>>>(qkp, lut);
  sparse_attn_kernel<<<dim3(16, 64), 256, 0, stream>>>(q, k, v, lut, out);
  kvsum_kernel<<<dim3(16, 16), 256, 0, stream>>>(k, v, kvp, ksp);
  reduce_kernel<<<256, 256, 0, stream>>>(kvp, ksp, kvr, ksum);
  m2_kernel<<<16, 256, 0, stream>>>(kvr, w, m2t);
  linear_out_kernel<<<dim3(16, 16), 256, 0, stream>>>(q, m2t, ksum, b, out);
}

// Round 5
// 184.016 us; speedup vs baseline: 1.7331x; 1.7331x over previous
//
#include <hip/hip_runtime.h>

// SparseLinearAttention: B=1, L=4096, H=16, D=64, BLKQ=BLKK=64, M=N=64, T=8.
// fp32 I/O; sparse-attn, kvsum, linear-out use bf16 MFMA 16x16x32, fp32 accum.

#define NH   16
#define DH   64
#define NBLK 64
#define TSEL 8

typedef unsigned short u16;
typedef unsigned int   u32;
typedef __attribute__((ext_vector_type(8))) short short8;  // 8 bf16
typedef __attribute__((ext_vector_type(4))) float f4;

#define MFMA_BF16(a, b, c) __builtin_amdgcn_mfma_f32_16x16x32_bf16(a, b, c, 0, 0, 0)

__device__ __forceinline__ u16 f2bf_rne(float f) {
  u32 u = __float_as_uint(f);
  u += 0x7fffu + ((u >> 16) & 1u);
  return (u16)(u >> 16);
}
__device__ __forceinline__ u32 pk2(float a, float b) {
  return (u32)f2bf_rne(a) | ((u32)f2bf_rne(b) << 16);
}
__device__ __forceinline__ float bf2f(u16 u) { return __uint_as_float(((u32)u) << 16); }

// Read an 8-bf16 MFMA fragment from a swizzled row-major bf16 tile
// (128 B rows; logical 16B-block j stored at j^(row&7)).
__device__ __forceinline__ short8 frag_row(const u16* lds, int row, int jblk) {
  int bp = jblk ^ (row & 7);
  return *(const short8*)((const char*)lds + row * 128 + bp * 16);
}

// ---------------- K1: block-mean partials (row-split by 16) -----------------
__global__ __launch_bounds__(256) void means_kernel(const float* __restrict__ q,
                                                    const float* __restrict__ k,
                                                    float* __restrict__ qkp) {
  int m = blockIdx.x, rs = blockIdx.y, z = blockIdx.z;
  const float* src = z ? k : q;
  int tid = threadIdx.x;
  const float* base = src + ((size_t)(m * 64 + rs * 16)) * 1024 + tid * 4;
  float4 acc = {0.f, 0.f, 0.f, 0.f};
#pragma unroll
  for (int i = 0; i < 16; i++) {
    float4 a = *(const float4*)(base + (size_t)i * 1024);
    acc.x += a.x; acc.y += a.y; acc.z += a.z; acc.w += a.w;
  }
  *(float4*)(qkp + ((size_t)((z * 4 + rs) * 64 + m)) * 1024 + tid * 4) = acc;
}

// ---------------- K2: block scores + top-8 per (h,m) -> lut -----------------
__global__ __launch_bounds__(64) void topk_kernel(const float* __restrict__ qkp,
                                                  int* __restrict__ lut) {
  __shared__ __align__(16) float qr_s[64];
  int m = blockIdx.x, h = blockIdx.y, n = threadIdx.x;
  float qsum = 0.f;
#pragma unroll
  for (int rs = 0; rs < 4; rs++)
    qsum += qkp[((size_t)(rs * 64 + m)) * 1024 + h * 64 + n];
  qr_s[n] = qsum;
  __syncthreads();
  float s = 0.f;
#pragma unroll
  for (int rs = 0; rs < 4; rs++) {
    const float* kr = qkp + ((size_t)((4 + rs) * 64 + n)) * 1024 + h * 64;
#pragma unroll
    for (int d = 0; d < 64; d += 4) {
      float4 a = *(const float4*)(kr + d);
      float4 b = *(const float4*)(&qr_s[d]);
      s += a.x * b.x + a.y * b.y + a.z * b.z + a.w * b.w;
    }
  }
  float my = s;
  for (int t = 0; t < TSEL; t++) {
    float v = my; int idx = n;
#pragma unroll
    for (int off = 1; off < 64; off <<= 1) {
      float ov = __shfl_xor(v, off);
      int oi = __shfl_xor(idx, off);
      if (ov > v || (ov == v && oi < idx)) { v = ov; idx = oi; }
    }
    if (n == 0) lut[(h * NBLK + m) * TSEL + t] = idx;
    if (n == idx) my = -INFINITY;
  }
}

// ---------------- K3: block-sparse attention, flash 4-wave, dbuf LDS --------
// grid (16 h, 64 m), 256 thr = 4 waves. Wave w owns Q rows [w*16, w*16+16)
// across all 8 selected key blocks -> wave-private online softmax, no merge.
// K/V^T staged cooperatively, double-buffered; one barrier per iteration.
__global__ __launch_bounds__(256, 3) void sparse_attn_kernel(const float* __restrict__ q,
                                                             const float* __restrict__ k,
                                                             const float* __restrict__ v,
                                                             const int* __restrict__ lut,
                                                             float* __restrict__ out) {
  __shared__ __align__(16) char smem[49152];
  // [0,8K) Q | [8K,24K) buf0: K 8K + V^T 8K | [24K,40K) buf1 | [40K,48K) P[4 waves]
  int h = blockIdx.x, m = blockIdx.y;
  int tid = threadIdx.x, w = tid >> 6, lane = tid & 63;
  int lq = lane & 15, quad = lane >> 4;
  u16* q_l = (u16*)smem;
  char* p_b = smem + 40960 + w * 2048;

  const int lb = (h * NBLK + m) * TSEL;
  int blks[8];
#pragma unroll
  for (int t = 0; t < 8; t++) blks[t] = lut[lb + t];

  { // stage Q (bf16 swizzled)
#pragma unroll
    for (int c = 0; c < 2; c++) {
      int lo = c * 4096 + tid * 16;
      int r = lo >> 7;
      int j = ((lo >> 4) & 7) ^ (r & 7);
      const float* gp = q + ((size_t)(m * 64 + r)) * 1024 + h * 64 + j * 8;
      float4 a = *(const float4*)gp;
      float4 b = *(const float4*)(gp + 4);
      *(uint4*)(smem + lo) = make_uint4(pk2(a.x, a.y), pk2(a.z, a.w),
                                        pk2(b.x, b.y), pk2(b.z, b.w));
    }
  }
  { // stage K/V block 0 into buf 0
    const float* kbase = k + ((size_t)blks[0] * 64) * 1024 + h * 64;
    char* kb0 = smem + 8192;
#pragma unroll
    for (int c = 0; c < 2; c++) {
      int lo = c * 4096 + tid * 16;
      int r = lo >> 7;
      int j = ((lo >> 4) & 7) ^ (r & 7);
      const float* gp = kbase + (size_t)r * 1024 + j * 8;
      float4 a = *(const float4*)gp;
      float4 b = *(const float4*)(gp + 4);
      *(uint4*)(kb0 + lo) = make_uint4(pk2(a.x, a.y), pk2(a.z, a.w),
                                       pk2(b.x, b.y), pk2(b.z, b.w));
    }
    int key = tid & 63, e0 = (tid >> 6) * 16;
    const float* vbase = v + ((size_t)blks[0] * 64 + key) * 1024 + h * 64 + e0;
    char* vt0 = kb0 + 8192;
    int kb_ = key >> 3, klo = key & 7;
#pragma unroll
    for (int c4 = 0; c4 < 4; c4++) {
      float4 a = *(const float4*)(vbase + c4 * 4);
      float vv[4] = {a.x, a.y, a.z, a.w};
#pragma unroll
      for (int jj = 0; jj < 4; jj++) {
        int e = e0 + c4 * 4 + jj;
        *(u16*)(vt0 + e * 128 + ((kb_ ^ (e & 7)) * 16) + klo * 2) = f2bf_rne(vv[jj]);
      }
    }
  }
  __syncthreads();

  float mrun = -INFINITY, lrun = 0.f;
  f4 o[4];
  f4 zz = {0.f, 0.f, 0.f, 0.f};
#pragma unroll
  for (int et = 0; et < 4; et++) o[et] = zz;
  const int qrow = w * 16 + lq;

  for (int t = 0; t < 8; t++) {
    char* kb_cur = smem + 8192 + (t & 1) * 16384;
    char* vt_cur = kb_cur + 8192;

    // issue next-block global loads (held in 32 VGPRs only)
    float4 kl[4], vl[4];
    if (t < 7) {
      const float* kbase = k + ((size_t)blks[t + 1] * 64) * 1024 + h * 64;
#pragma unroll
      for (int c = 0; c < 2; c++) {
        int lo = c * 4096 + tid * 16;
        int r = lo >> 7;
        int j = ((lo >> 4) & 7) ^ (r & 7);
        const float* gp = kbase + (size_t)r * 1024 + j * 8;
        kl[c * 2] = *(const float4*)gp;
        kl[c * 2 + 1] = *(const float4*)(gp + 4);
      }
      const float* vbase = v + ((size_t)blks[t + 1] * 64 + (tid & 63)) * 1024 +
                           h * 64 + (tid >> 6) * 16;
#pragma unroll
      for (int c4 = 0; c4 < 4; c4++) vl[c4] = *(const float4*)(vbase + c4 * 4);
    }

    // S^T = K · Q^T  (frag: key = kt*16+quad*4+r, q = qrow)
    f4 s[4];
#pragma unroll
    for (int kt = 0; kt < 4; kt++) s[kt] = zz;
#pragma unroll
    for (int ks = 0; ks < 2; ks++) {
      short8 bfr = frag_row(q_l, qrow, 4 * ks + quad);
#pragma unroll
      for (int kt = 0; kt < 4; kt++) {
        short8 afr = frag_row((u16*)kb_cur, kt * 16 + lq, 4 * ks + quad);
        s[kt] = MFMA_BF16(afr, bfr, s[kt]);
      }
    }

    // online softmax (16 scores/lane), write P row lq (wave-private slab)
    float mp = -INFINITY;
#pragma unroll
    for (int kt = 0; kt < 4; kt++)
#pragma unroll
      for (int r = 0; r < 4; r++) mp = fmaxf(mp, s[kt][r]);
    mp = fmaxf(mp, __shfl_xor(mp, 16));
    mp = fmaxf(mp, __shfl_xor(mp, 32));
    mp *= 0.125f;
    float mn = fmaxf(mrun, mp);
    float al = __expf(mrun - mn);
    mrun = mn;
    float rs_ = 0.f;
#pragma unroll
    for (int kt = 0; kt < 4; kt++) {
      float p0 = __expf(fmaf(s[kt][0], 0.125f, -mn));
      float p1 = __expf(fmaf(s[kt][1], 0.125f, -mn));
      float p2 = __expf(fmaf(s[kt][2], 0.125f, -mn));
      float p3 = __expf(fmaf(s[kt][3], 0.125f, -mn));
      rs_ += p0 + p1 + p2 + p3;
      u32 lo32 = (__float_as_uint(p0) >> 16) | (__float_as_uint(p1) & 0xffff0000u);
      u32 hi32 = (__float_as_uint(p2) >> 16) | (__float_as_uint(p3) & 0xffff0000u);
      int addr = lq * 128 + (((kt * 2 + (quad >> 1)) ^ (lq & 7)) * 16) + (quad & 1) * 8;
      *(uint2*)(p_b + addr) = make_uint2(lo32, hi32);
    }
    rs_ += __shfl_xor(rs_, 16);
    rs_ += __shfl_xor(rs_, 32);
    lrun = lrun * al + rs_;
#pragma unroll
    for (int et = 0; et < 4; et++)
#pragma unroll
      for (int r = 0; r < 4; r++) o[et][r] *= al;

    // write staged next K/V into the other buffer
    if (t < 7) {
      char* kb_nxt = smem + 8192 + ((t + 1) & 1) * 16384;
      char* vt_nxt = kb_nxt + 8192;
#pragma unroll
      for (int c = 0; c < 2; c++) {
        int lo = c * 4096 + tid * 16;
        *(uint4*)(kb_nxt + lo) =
            make_uint4(pk2(kl[c * 2].x, kl[c * 2].y), pk2(kl[c * 2].z, kl[c * 2].w),
                       pk2(kl[c * 2 + 1].x, kl[c * 2 + 1].y), pk2(kl[c * 2 + 1].z, kl[c * 2 + 1].w));
      }
      int key = tid & 63, e0 = (tid >> 6) * 16;
      int kb2 = key >> 3, klo = key & 7;
#pragma unroll
      for (int c4 = 0; c4 < 4; c4++) {
        float vv[4] = {vl[c4].x, vl[c4].y, vl[c4].z, vl[c4].w};
#pragma unroll
        for (int jj = 0; jj < 4; jj++) {
          int e = e0 + c4 * 4 + jj;
          *(u16*)(vt_nxt + e * 128 + ((kb2 ^ (e & 7)) * 16) + klo * 2) = f2bf_rne(vv[jj]);
        }
      }
    }

    // O^T += V^T · P^T  (e = et*16+quad*4+r, q = qrow)
#pragma unroll
    for (int ks = 0; ks < 2; ks++) {
      short8 bp = frag_row((u16*)p_b, lq, 4 * ks + quad);
#pragma unroll
      for (int et = 0; et < 4; et++) {
        short8 av = frag_row((u16*)vt_cur, et * 16 + lq, 4 * ks + quad);
        o[et] = MFMA_BF16(av, bp, o[et]);
      }
    }
    __syncthreads();
  }

  // epilogue: o[et] is an aligned float4 of out row qrow -> direct stores
  float inv = 1.0f / lrun;
  float* gp = out + ((size_t)(m * 64 + qrow)) * 1024 + h * 64 + quad * 4;
#pragma unroll
  for (int et = 0; et < 4; et++) {
    float4 ov;
    ov.x = o[et][0] * inv; ov.y = o[et][1] * inv;
    ov.z = o[et][2] * inv; ov.w = o[et][3] * inv;
    *(float4*)(gp + et * 16) = ov;
  }
}

// ---------------- K4: kvsum partial slabs via MFMA --------------------------
__global__ __launch_bounds__(256) void kvsum_kernel(const float* __restrict__ k,
                                                    const float* __restrict__ v,
                                                    float* __restrict__ kvp,
                                                    float* __restrict__ ksp) {
  __shared__ __align__(16) char slabs[65536];   // per wave: V^T 8KB + kfmT 8KB
  __shared__ float ks_red[256];
  int bx = blockIdx.x, h = blockIdx.y;
  int tid = threadIdx.x, w = tid >> 6, lane = tid & 63;
  int lq = lane & 15, quad = lane >> 4;
  char* vt_b = slabs + w * 16384;
  char* kf_b = vt_b + 8192;
  int n = bx * 4 + w;
  const float* kb_ = k + ((size_t)n * 64) * 1024 + h * 64;
  const float* vb_ = v + ((size_t)n * 64) * 1024 + h * 64;

  { // stage V^T
    const float* gp = vb_ + (size_t)lane * 1024;
    int kbi = lane >> 3, klo = lane & 7;
#pragma unroll
    for (int c4 = 0; c4 < 16; c4++) {
      float4 a = *(const float4*)(gp + c4 * 4);
      float vv[4] = {a.x, a.y, a.z, a.w};
#pragma unroll
      for (int jj = 0; jj < 4; jj++) {
        int e = c4 * 4 + jj;
        int bp = kbi ^ (e & 7);
        *(u16*)(vt_b + e * 128 + bp * 16 + klo * 2) = f2bf_rne(vv[jj]);
      }
    }
  }
  { // row softmax of K (lane = row), transposed store -> kfmT
    const float* kr = kb_ + (size_t)lane * 1024;
    float kv[64];
#pragma unroll
    for (int c4 = 0; c4 < 16; c4++) {
      float4 a = *(const float4*)(kr + c4 * 4);
      kv[c4 * 4] = a.x; kv[c4 * 4 + 1] = a.y; kv[c4 * 4 + 2] = a.z; kv[c4 * 4 + 3] = a.w;
    }
    float mx = -INFINITY;
#pragma unroll
    for (int d = 0; d < 64; d++) mx = fmaxf(mx, kv[d]);
    float sum = 0.f;
#pragma unroll
    for (int d = 0; d < 64; d++) { kv[d] = __expf(kv[d] - mx); sum += kv[d]; }
    float inv = 1.0f / sum;
    int rb = lane >> 3, rlo = lane & 7;
#pragma unroll
    for (int d = 0; d < 64; d++) {
      int bp = rb ^ (d & 7);
      *(u16*)(kf_b + d * 128 + bp * 16 + rlo * 2) = f2bf_rne(kv[d] * inv);
    }
  }
  float ksacc = 0.f;
#pragma unroll
  for (int jb = 0; jb < 8; jb++) {
    short8 x = frag_row((u16*)kf_b, lane, jb);
#pragma unroll
    for (int e = 0; e < 8; e++) ksacc += bf2f((u16)x[e]);
  }
  f4 acc[4][4];
  f4 zz = {0.f, 0.f, 0.f, 0.f};
#pragma unroll
  for (int dt = 0; dt < 4; dt++)
#pragma unroll
    for (int et = 0; et < 4; et++) acc[dt][et] = zz;
#pragma unroll
  for (int ks2 = 0; ks2 < 2; ks2++) {
    short8 a_[4], b_[4];
#pragma unroll
    for (int dt = 0; dt < 4; dt++) a_[dt] = frag_row((u16*)kf_b, dt * 16 + lq, 4 * ks2 + quad);
#pragma unroll
    for (int et = 0; et < 4; et++) b_[et] = frag_row((u16*)vt_b, et * 16 + lq, 4 * ks2 + quad);
#pragma unroll
    for (int dt = 0; dt < 4; dt++)
#pragma unroll
      for (int et = 0; et < 4; et++)
        acc[dt][et] = MFMA_BF16(a_[dt], b_[et], acc[dt][et]);
  }
  float* red = (float*)(slabs + w * 16384);
  if (w > 0) {
#pragma unroll
    for (int dt = 0; dt < 4; dt++)
#pragma unroll
      for (int et = 0; et < 4; et++)
#pragma unroll
        for (int r = 0; r < 4; r++)
          red[(dt * 16 + quad * 4 + r) * 64 + et * 16 + lq] = acc[dt][et][r];
  }
  ks_red[w * 64 + lane] = ksacc;
  __syncthreads();
  if (w == 0) {
    float* r1 = (float*)(slabs + 16384);
    float* r2 = (float*)(slabs + 32768);
    float* r3 = (float*)(slabs + 49152);
    float* kvb = kvp + ((size_t)(bx * 16 + h)) * 4096;
#pragma unroll
    for (int dt = 0; dt < 4; dt++)
#pragma unroll
      for (int et = 0; et < 4; et++)
#pragma unroll
        for (int r = 0; r < 4; r++) {
          int idx = (dt * 16 + quad * 4 + r) * 64 + et * 16 + lq;
          kvb[idx] = acc[dt][et][r] + r1[idx] + r2[idx] + r3[idx];
        }
    ksp[(bx * 16 + h) * 64 + lane] = ks_red[lane] + ks_red[64 + lane] +
                                     ks_red[128 + lane] + ks_red[192 + lane];
  }
}

// ---------------- K5: fused slab-reduce + M2^T = (kvsum@W^T)^T bf16 ---------
__global__ __launch_bounds__(256) void m2_kernel(const float* __restrict__ kvp,
                                                 const float* __restrict__ ksp,
                                                 const float* __restrict__ wgt,
                                                 u16* __restrict__ m2t,
                                                 float* __restrict__ ksum) {
  __shared__ float kv_s[64 * 65];
  __shared__ float w_s[64 * 65];
  int h = blockIdx.x, tid = threadIdx.x;
#pragma unroll
  for (int jj = 0; jj < 16; jj++) {
    int idx = jj * 256 + tid;   // coalesced
    float sv = 0.f;
#pragma unroll
    for (int t = 0; t < 16; t++) sv += kvp[((size_t)(t * 16 + h)) * 4096 + idx];
    kv_s[(idx >> 6) * 65 + (idx & 63)] = sv;
    w_s[(idx >> 6) * 65 + (idx & 63)] = wgt[idx];
  }
  if (tid < 64) {
    float ss = 0.f;
#pragma unroll
    for (int t = 0; t < 16; t++) ss += ksp[(t * 16 + h) * 64 + tid];
    ksum[h * 64 + tid] = ss;
  }
  __syncthreads();
  int d = tid >> 2, e0 = (tid & 3) * 16;
  float acc[16];
#pragma unroll
  for (int e = 0; e < 16; e++) acc[e] = 0.f;
  for (int j = 0; j < 64; j++) {
    float kvj = kv_s[d * 65 + j];
#pragma unroll
    for (int e = 0; e < 16; e++)
      acc[e] = fmaf(kvj, w_s[(e0 + e) * 65 + j], acc[e]);
  }
  char* base = (char*)m2t + (size_t)h * 8192;
#pragma unroll
  for (int e = 0; e < 16; e++) {
    int ee = e0 + e;
    int bp = (d >> 3) ^ (ee & 7);
    *(u16*)(base + ee * 128 + bp * 16 + (d & 7) * 2) = f2bf_rne(acc[e]);
  }
}

// ---------------- K6: linear attention output via MFMA, out += o_l ----------
__global__ __launch_bounds__(256) void linear_out_kernel(const float* __restrict__ q,
                                                         const u16* __restrict__ m2t,
                                                         const float* __restrict__ ksum,
                                                         const float* __restrict__ bproj,
                                                         float* __restrict__ out) {
  __shared__ __align__(16) char lsm[42496];
  u16* m2_l = (u16*)lsm;
  int lg = blockIdx.x, h = blockIdx.y;
  int tid = threadIdx.x, w = tid >> 6, lane = tid & 63;
  int lq = lane & 15, quad = lane >> 4;
  char* e_b = lsm + 8192 + w * 8192;
  float* ks_s = (float*)(lsm + 40960);
  float* b_s  = (float*)(lsm + 41216);
  float* sc_s = (float*)(lsm + 41472);

  {
    const uint4* src = (const uint4*)((const char*)m2t + (size_t)h * 8192);
    ((uint4*)lsm)[tid] = src[tid];
    ((uint4*)lsm)[256 + tid] = src[256 + tid];
  }
  if (tid < 64) { ks_s[tid] = ksum[h * 64 + tid]; b_s[tid] = bproj[tid]; }
  __syncthreads();

  int l = (lg * 4 + w) * 64 + lane;
  const float* qp = q + (size_t)l * 1024 + h * 64;
  float qv[64];
#pragma unroll
  for (int c4 = 0; c4 < 16; c4++) {
    float4 a = *(const float4*)(qp + c4 * 4);
    qv[c4 * 4] = a.x; qv[c4 * 4 + 1] = a.y; qv[c4 * 4 + 2] = a.z; qv[c4 * 4 + 3] = a.w;
  }
  float mx = -INFINITY;
#pragma unroll
  for (int d = 0; d < 64; d++) mx = fmaxf(mx, qv[d]);
  float sum = 0.f, eks = 0.f;
#pragma unroll
  for (int d = 0; d < 64; d++) {
    float e = __expf(qv[d] - mx);
    qv[d] = e;
    sum += e;
    eks += e * ks_s[d];
  }
  float inv = 1.0f / sum;
  float den = fmaf(eks, inv, 1e-6f);
  sc_s[w * 64 + lane] = inv / den;

  {
    int rowm = lane & 7;
#pragma unroll
    for (int jb = 0; jb < 8; jb++) {
      int d0 = jb * 8;
      uint4 pv = make_uint4(pk2(qv[d0], qv[d0 + 1]), pk2(qv[d0 + 2], qv[d0 + 3]),
                            pk2(qv[d0 + 4], qv[d0 + 5]), pk2(qv[d0 + 6], qv[d0 + 7]));
      *(uint4*)(e_b + lane * 128 + ((jb ^ rowm) * 16)) = pv;
    }
  }

  f4 oc[4][4];
  f4 zz = {0.f, 0.f, 0.f, 0.f};
#pragma unroll
  for (int et = 0; et < 4; et++)
#pragma unroll
    for (int lt = 0; lt < 4; lt++) oc[et][lt] = zz;
#pragma unroll
  for (int ks2 = 0; ks2 < 2; ks2++) {
    short8 a_[4], b_[4];
#pragma unroll
    for (int et = 0; et < 4; et++) a_[et] = frag_row(m2_l, et * 16 + lq, 4 * ks2 + quad);
#pragma unroll
    for (int lt = 0; lt < 4; lt++) b_[lt] = frag_row((u16*)e_b, lt * 16 + lq, 4 * ks2 + quad);
#pragma unroll
    for (int et = 0; et < 4; et++)
#pragma unroll
      for (int lt = 0; lt < 4; lt++)
        oc[et][lt] = MFMA_BF16(a_[et], b_[lt], oc[et][lt]);
  }

#pragma unroll
  for (int lt = 0; lt < 4; lt++) {
    int lrow = lt * 16 + lq;
    float sc2 = sc_s[w * 64 + lrow];
#pragma unroll
    for (int et = 0; et < 4; et++) {
      int e0 = et * 16 + quad * 4;
      float p0 = oc[et][lt][0] * sc2 + b_s[e0 + 0];
      float p1 = oc[et][lt][1] * sc2 + b_s[e0 + 1];
      float p2 = oc[et][lt][2] * sc2 + b_s[e0 + 2];
      float p3 = oc[et][lt][3] * sc2 + b_s[e0 + 3];
      int addr = lrow * 128 + ((et * 2 + (quad >> 1)) ^ (lrow & 7)) * 16 + (quad & 1) * 8;
      *(uint2*)(e_b + addr) = make_uint2(pk2(p0, p1), pk2(p2, p3));
    }
  }
  {
    float* gp = out + (size_t)l * 1024 + h * 64;
    int rowm = lane & 7;
#pragma unroll
    for (int jb = 0; jb < 8; jb++) {
      uint4 x = *(const uint4*)(e_b + lane * 128 + ((jb ^ rowm) * 16));
      float4 o1 = *(const float4*)(gp + jb * 8);
      float4 o2 = *(const float4*)(gp + jb * 8 + 4);
      o1.x += __uint_as_float(x.x << 16);
      o1.y += __uint_as_float(x.x & 0xffff0000u);
      o1.z += __uint_as_float(x.y << 16);
      o1.w += __uint_as_float(x.y & 0xffff0000u);
      o2.x += __uint_as_float(x.z << 16);
      o2.y += __uint_as_float(x.z & 0xffff0000u);
      o2.z += __uint_as_float(x.w << 16);
      o2.w += __uint_as_float(x.w & 0xffff0000u);
      *(float4*)(gp + jb * 8) = o1;
      *(float4*)(gp + jb * 8 + 4) = o2;
    }
  }
}

extern "C" void kernel_launch(void* const* d_in, const int* in_sizes, int n_in,
                              void* d_out, int out_size, void* d_ws, size_t ws_size,
                              hipStream_t stream) {
  const float* q = (const float*)d_in[0];
  const float* k = (const float*)d_in[1];
  const float* v = (const float*)d_in[2];
  const float* w = (const float*)d_in[3];
  const float* b = (const float*)d_in[4];
  float* out = (float*)d_out;

  // ws: qkp 512K f32 | lut 8K int | kvp 1M f32 | ksp 16K f32 | ksum 1K f32 | m2t 64K u16
  float* qkp = (float*)d_ws;
  int* lut = (int*)(qkp + 524288);
  float* kvp = (float*)(lut + 8192);
  float* ksp = kvp + 1048576;
  float* ksum = ksp + 16384;
  u16* m2t = (u16*)(ksum + 1024);

  means_kernel<<<dim3(64, 4, 2), 256, 0, stream>>>(q, k, qkp);
  topk_kernel<<<dim3(64, 16), 64, 0, stream>>>(qkp, lut);
  sparse_attn_kernel<<<dim3(16, 64), 256, 0, stream>>>(q, k, v, lut, out);
  kvsum_kernel<<<dim3(16, 16), 256, 0, stream>>>(k, v, kvp, ksp);
  m2_kernel<<<16, 256, 0, stream>>>(kvp, ksp, w, m2t, ksum);
  linear_out_kernel<<<dim3(16, 16), 256, 0, stream>>>(q, m2t, ksum, b, out);
}